// Round 1
// baseline (120.936 us; speedup 1.0000x reference)
//
#include <hip/hip_runtime.h>

// Photoreceptor Rieke model: 40,000 independent nonlinear ODE chains,
// sequential over T=1000. 1 thread = 1 chain, coalesced over p.
#define B_ 16
#define T_ 1000
#define P_ 2500
#define NCH (B_ * P_)   // 40000 = 625 blocks * 64 threads exactly

__device__ __forceinline__ float rcp_fast(float v) {
    return __builtin_amdgcn_rcpf(v);   // ~1 ulp, single v_rcp_f32
}

extern "C" __global__ void __launch_bounds__(64)
prk_kernel(const float* __restrict__ x,
           const float* __restrict__ sigma_p,  const float* __restrict__ phi_p,
           const float* __restrict__ eta_p,    const float* __restrict__ c2c_p,
           const float* __restrict__ hill_p,   const float* __restrict__ cdark_p,
           const float* __restrict__ beta_p,   const float* __restrict__ bslow_p,
           const float* __restrict__ hcoef_p,  const float* __restrict__ haff_p,
           const float* __restrict__ gamma_p,  const float* __restrict__ gdark_p,
           float* __restrict__ out)
{
    const int tid = blockIdx.x * 64 + threadIdx.x;   // grid sized exactly
    const int b = tid / P_;
    const int p = tid - b * P_;

    const float sigma        = sigma_p[0];
    const float phi          = phi_p[0];
    const float eta          = eta_p[0];
    const float cgmp2cur     = c2c_p[0];
    const float cgmphill     = hill_p[0];
    const float cdark        = cdark_p[0];
    const float beta         = beta_p[0];
    const float betaSlow     = bslow_p[0];
    const float hillcoef     = hcoef_p[0];
    const float hillaffinity = haff_p[0];
    const float gamma        = gamma_p[0] * 0.125f;  // gamma / timeBin(8)
    const float gdark        = gdark_p[0];
    const float DT = 0.008f;                          // 0.001 * 8

    // derived constants (once per thread; uniform)
    const float darkCurrent = powf(gdark, cgmphill) * cgmp2cur * 0.5f;
    const float gdark_ = powf(2.0f * darkCurrent / cgmp2cur, 1.0f / cgmphill);
    const float cur2ca = beta * cdark / darkCurrent;
    const float smax   = eta / phi * gdark_ *
                         (1.0f + powf(cdark / hillaffinity, hillcoef));

    const float Ar  = 1.0f - DT * sigma;
    const float Ap  = 1.0f - DT * phi;
    const float Pe  = DT * eta;
    const float Ac  = 1.0f - DT * beta;
    const float Kc  = DT * cur2ca * cgmp2cur;
    const float Acs = 1.0f - DT * betaSlow;
    const float Bcs = DT * betaSlow;
    const float inv_cd = 1.0f / cdark;
    const float inv_ha = 1.0f / hillaffinity;
    const float outk   = -0.5f * cgmp2cur;

    const float* __restrict__ xp = x   + (size_t)b * T_ * P_ + p;
    float*       __restrict__ op = out + (size_t)b * T_ * P_ + p;

    // initial state
    const float x0 = xp[0];
    float r  = x0 * gamma / sigma;
    float pv = (eta + r) / phi;
    float g  = gdark_;
    float s  = gdark_ * eta / phi;
    float c  = cdark;
    float cs = cdark;
    op[0] = 0.0f;                       // g_all[0] = 0 -> output 0

    if (cgmphill == 3.0f && hillcoef == 4.0f) {
        // ---- hot specialized path (uniform branch) ----
        auto step = [&](float xt, int oidx) {
            float r1  = fmaf(Ar, r, gamma * xt);
            float p1  = fmaf(Ap, pv, fmaf(DT, r, Pe));
            float g3  = g * g * g;
            float den = fmaf(cs, inv_cd, 1.0f);
            float c1  = fmaf(Ac, c, Kc * g3 * rcp_fast(den));
            float cs1 = fmaf(Acs, cs, Bcs * c);
            float yy  = c1 * inv_ha;
            float y2  = yy * yy;
            float y4  = y2 * y2;
            float s1  = smax * rcp_fast(1.0f + y4);
            float g1  = fmaf(DT, fmaf(-pv, g, s), g);
            op[(size_t)oidx * P_] = outk * (g1 * g1 * g1);
            r = r1; pv = p1; c = c1; cs = cs1; s = s1; g = g1;
        };

        constexpr int U = 16;           // prefetch chunk (software pipeline depth 1)
        float xv[U];
        #pragma unroll
        for (int u = 0; u < U; ++u) xv[u] = xp[(size_t)u * P_];

        int t = 0;
        #pragma unroll 1
        for (int ci = 0; ci < 62; ++ci) {       // 62*16 = 992 steps
            float xn[U];
            const int tn = (ci + 1) * U;
            #pragma unroll
            for (int u = 0; u < U; ++u) {       // prefetch next chunk (clamped tail)
                int tt = tn + u;
                tt = tt > 998 ? 998 : tt;
                xn[u] = xp[(size_t)tt * P_];
            }
            #pragma unroll
            for (int u = 0; u < U; ++u) step(xv[u], t + u + 1);
            t += U;
            #pragma unroll
            for (int u = 0; u < U; ++u) xv[u] = xn[u];
        }
        // tail: 7 remaining steps (t = 992..998)
        #pragma unroll
        for (int u = 0; u < 7; ++u) step(xv[u], t + u + 1);
    } else {
        // ---- generic fallback (exact powf; never taken for bench params) ----
        for (int t = 0; t < T_ - 1; ++t) {
            float xt  = xp[(size_t)t * P_];
            float r1  = r + DT * (-sigma * r) + gamma * xt;
            float p1  = pv + DT * (r + eta - phi * pv);
            float c1  = c + DT * (cur2ca * cgmp2cur * powf(g, cgmphill) /
                                  (1.0f + cs / cdark) - beta * c);
            float cs1 = cs - DT * (betaSlow * (cs - c));
            float s1  = smax / (1.0f + powf(c1 / hillaffinity, hillcoef));
            float g1  = g + DT * (s - pv * g);
            op[(size_t)(t + 1) * P_] = -(cgmp2cur * powf(g1, cgmphill)) * 0.5f;
            r = r1; pv = p1; c = c1; cs = cs1; s = s1; g = g1;
        }
    }
}

extern "C" void kernel_launch(void* const* d_in, const int* in_sizes, int n_in,
                              void* d_out, int out_size, void* d_ws, size_t ws_size,
                              hipStream_t stream) {
    const float* x = (const float*)d_in[0];
    prk_kernel<<<dim3(NCH / 64), dim3(64), 0, stream>>>(
        x,
        (const float*)d_in[1],  (const float*)d_in[2],  (const float*)d_in[3],
        (const float*)d_in[4],  (const float*)d_in[5],  (const float*)d_in[6],
        (const float*)d_in[7],  (const float*)d_in[8],  (const float*)d_in[9],
        (const float*)d_in[10], (const float*)d_in[11], (const float*)d_in[12],
        (float*)d_out);
}

// Round 2
// 83.001 us; speedup vs baseline: 1.4570x; 1.4570x over previous
//
#include <hip/hip_runtime.h>

// Photoreceptor Rieke model: 40,000 independent nonlinear ODE chains,
// sequential over T=1000. 1 thread = 1 chain, coalesced over p.
// R2: depth-2 software pipeline pinned with sched_barrier(0); the R1 compiler
// collapsed the prefetch (VGPR=36 proved it) -> ~230 stall cycles/step.
#define B_ 16
#define T_ 1000
#define P_ 2500
#define NCH (B_ * P_)   // 40000 = 625 blocks * 64 threads exactly

__device__ __forceinline__ float rcp_fast(float v) {
    return __builtin_amdgcn_rcpf(v);   // ~1 ulp, single v_rcp_f32
}

extern "C" __global__ void __launch_bounds__(64, 1)
prk_kernel(const float* __restrict__ x,
           const float* __restrict__ sigma_p,  const float* __restrict__ phi_p,
           const float* __restrict__ eta_p,    const float* __restrict__ c2c_p,
           const float* __restrict__ hill_p,   const float* __restrict__ cdark_p,
           const float* __restrict__ beta_p,   const float* __restrict__ bslow_p,
           const float* __restrict__ hcoef_p,  const float* __restrict__ haff_p,
           const float* __restrict__ gamma_p,  const float* __restrict__ gdark_p,
           float* __restrict__ out)
{
    const int tid = blockIdx.x * 64 + threadIdx.x;   // grid sized exactly
    const int b = tid / P_;
    const int p = tid - b * P_;

    const float sigma        = sigma_p[0];
    const float phi          = phi_p[0];
    const float eta          = eta_p[0];
    const float cgmp2cur     = c2c_p[0];
    const float cgmphill     = hill_p[0];
    const float cdark        = cdark_p[0];
    const float beta         = beta_p[0];
    const float betaSlow     = bslow_p[0];
    const float hillcoef     = hcoef_p[0];
    const float hillaffinity = haff_p[0];
    const float gamma        = gamma_p[0] * 0.125f;  // gamma / timeBin(8)
    const float gdark        = gdark_p[0];
    const float DT = 0.008f;                          // 0.001 * 8

    // derived constants (once per thread; uniform)
    const float darkCurrent = powf(gdark, cgmphill) * cgmp2cur * 0.5f;
    const float gdark_ = powf(2.0f * darkCurrent / cgmp2cur, 1.0f / cgmphill);
    const float cur2ca = beta * cdark / darkCurrent;
    const float smax   = eta / phi * gdark_ *
                         (1.0f + powf(cdark / hillaffinity, hillcoef));

    const float Ar  = 1.0f - DT * sigma;
    const float Ap  = 1.0f - DT * phi;
    const float Pe  = DT * eta;
    const float Ac  = 1.0f - DT * beta;
    const float Kc  = DT * cur2ca * cgmp2cur;
    const float Acs = 1.0f - DT * betaSlow;
    const float Bcs = DT * betaSlow;
    const float inv_cd = 1.0f / cdark;
    const float inv_ha = 1.0f / hillaffinity;
    const float outk   = -0.5f * cgmp2cur;

    const float* __restrict__ xp = x   + (size_t)b * T_ * P_ + p;
    float*       __restrict__ op = out + (size_t)b * T_ * P_ + p;

    // initial state
    const float x0 = xp[0];
    float r  = x0 * gamma / sigma;
    float pv = (eta + r) / phi;
    float g  = gdark_;
    float s  = gdark_ * eta / phi;
    float c  = cdark;
    float cs = cdark;
    __builtin_nontemporal_store(0.0f, op);   // g_all[0] = 0 -> output 0

    if (cgmphill == 3.0f && hillcoef == 4.0f) {
        // ---- hot specialized path (uniform branch) ----
        auto step = [&](float xt, int oidx) {
            float r1  = fmaf(Ar, r, gamma * xt);
            float p1  = fmaf(Ap, pv, fmaf(DT, r, Pe));
            float g3  = g * g * g;
            float den = fmaf(cs, inv_cd, 1.0f);
            float c1  = fmaf(Ac, c, Kc * g3 * rcp_fast(den));
            float cs1 = fmaf(Acs, cs, Bcs * c);
            float yy  = c1 * inv_ha;
            float y2  = yy * yy;
            float y4  = y2 * y2;
            float s1  = smax * rcp_fast(1.0f + y4);
            float g1  = fmaf(DT, fmaf(-pv, g, s), g);
            __builtin_nontemporal_store(outk * (g1 * g1 * g1),
                                        op + (size_t)oidx * P_);
            r = r1; pv = p1; c = c1; cs = cs1; s = s1; g = g1;
        };

        constexpr int U = 16;           // chunk; pipeline depth 2 (3 buffers)
        float b0[U], b1[U], b2[U];

        auto loadch_nc = [&](float (&buf)[U], int tn) {   // no clamp (tn+15<=991)
            #pragma unroll
            for (int u = 0; u < U; ++u) buf[u] = xp[(size_t)(tn + u) * P_];
        };
        auto loadch_cl = [&](float (&buf)[U], int tn) {   // clamped tail chunk
            #pragma unroll
            for (int u = 0; u < U; ++u) {
                int tt = tn + u; tt = tt > 998 ? 998 : tt;
                buf[u] = xp[(size_t)tt * P_];
            }
        };
        auto compch = [&](float (&buf)[U], int tbase) {
            #pragma unroll
            for (int u = 0; u < U; ++u) step(buf[u], tbase + u + 1);
        };

        loadch_nc(b0, 0);
        loadch_nc(b1, U);
        __builtin_amdgcn_sched_barrier(0);

        int t = 0;
        // chunks 0..59 in groups of 3 (buffer rotation is compile-time: no movs)
        #pragma unroll 1
        for (int ci = 0; ci < 60; ci += 3) {
            loadch_nc(b2, (ci + 2) * U);  __builtin_amdgcn_sched_barrier(0);
            compch(b0, t);                __builtin_amdgcn_sched_barrier(0);
            t += U;
            loadch_nc(b0, (ci + 3) * U);  __builtin_amdgcn_sched_barrier(0);
            compch(b1, t);                __builtin_amdgcn_sched_barrier(0);
            t += U;
            loadch_nc(b1, (ci + 4) * U);  __builtin_amdgcn_sched_barrier(0);
            compch(b2, t);                __builtin_amdgcn_sched_barrier(0);
            t += U;
        }
        // chunks 60, 61 + clamped chunk 62 (t=992..998 used)
        loadch_cl(b2, 62 * U);            __builtin_amdgcn_sched_barrier(0);
        compch(b0, t);  t += U;           // chunk 60
        compch(b1, t);  t += U;           // chunk 61
        #pragma unroll
        for (int u = 0; u < 7; ++u) step(b2[u], t + u + 1);  // t=992..998
    } else {
        // ---- generic fallback (exact powf; never taken for bench params) ----
        for (int t = 0; t < T_ - 1; ++t) {
            float xt  = xp[(size_t)t * P_];
            float r1  = r + DT * (-sigma * r) + gamma * xt;
            float p1  = pv + DT * (r + eta - phi * pv);
            float c1  = c + DT * (cur2ca * cgmp2cur * powf(g, cgmphill) /
                                  (1.0f + cs / cdark) - beta * c);
            float cs1 = cs - DT * (betaSlow * (cs - c));
            float s1  = smax / (1.0f + powf(c1 / hillaffinity, hillcoef));
            float g1  = g + DT * (s - pv * g);
            op[(size_t)(t + 1) * P_] = -(cgmp2cur * powf(g1, cgmphill)) * 0.5f;
            r = r1; pv = p1; c = c1; cs = cs1; s = s1; g = g1;
        }
    }
}

extern "C" void kernel_launch(void* const* d_in, const int* in_sizes, int n_in,
                              void* d_out, int out_size, void* d_ws, size_t ws_size,
                              hipStream_t stream) {
    const float* x = (const float*)d_in[0];
    prk_kernel<<<dim3(NCH / 64), dim3(64), 0, stream>>>(
        x,
        (const float*)d_in[1],  (const float*)d_in[2],  (const float*)d_in[3],
        (const float*)d_in[4],  (const float*)d_in[5],  (const float*)d_in[6],
        (const float*)d_in[7],  (const float*)d_in[8],  (const float*)d_in[9],
        (const float*)d_in[10], (const float*)d_in[11], (const float*)d_in[12],
        (float*)d_out);
}

// Round 3
// 72.541 us; speedup vs baseline: 1.6671x; 1.1442x over previous
//
#include <hip/hip_runtime.h>

// Photoreceptor Rieke model: 40,000 independent nonlinear ODE chains,
// sequential over T=1000. 1 thread = 1 chain, coalesced over p.
// R3: depth-4 software pipeline (5 rotating chunk buffers, compile-time
// rotation), sched_barrier(0)-fenced. R2's depth-2 window (~2 phases) was
// marginal vs ~900cyc latency; VALUBusy 18% said 70% memory-wait remained.
#define B_ 16
#define T_ 1000
#define P_ 2500
#define NCH (B_ * P_)   // 40000 = 625 blocks * 64 threads exactly

__device__ __forceinline__ float rcp_fast(float v) {
    return __builtin_amdgcn_rcpf(v);   // ~1 ulp, single v_rcp_f32
}

extern "C" __global__ void __launch_bounds__(64, 1)
prk_kernel(const float* __restrict__ x,
           const float* __restrict__ sigma_p,  const float* __restrict__ phi_p,
           const float* __restrict__ eta_p,    const float* __restrict__ c2c_p,
           const float* __restrict__ hill_p,   const float* __restrict__ cdark_p,
           const float* __restrict__ beta_p,   const float* __restrict__ bslow_p,
           const float* __restrict__ hcoef_p,  const float* __restrict__ haff_p,
           const float* __restrict__ gamma_p,  const float* __restrict__ gdark_p,
           float* __restrict__ out)
{
    const int tid = blockIdx.x * 64 + threadIdx.x;   // grid sized exactly
    const int b = tid / P_;
    const int p = tid - b * P_;

    const float sigma        = sigma_p[0];
    const float phi          = phi_p[0];
    const float eta          = eta_p[0];
    const float cgmp2cur     = c2c_p[0];
    const float cgmphill     = hill_p[0];
    const float cdark        = cdark_p[0];
    const float beta         = beta_p[0];
    const float betaSlow     = bslow_p[0];
    const float hillcoef     = hcoef_p[0];
    const float hillaffinity = haff_p[0];
    const float gamma        = gamma_p[0] * 0.125f;  // gamma / timeBin(8)
    const float gdark        = gdark_p[0];
    const float DT = 0.008f;                          // 0.001 * 8

    // derived constants (once per thread; uniform -> SGPRs)
    const float darkCurrent = powf(gdark, cgmphill) * cgmp2cur * 0.5f;
    const float gdark_ = powf(2.0f * darkCurrent / cgmp2cur, 1.0f / cgmphill);
    const float cur2ca = beta * cdark / darkCurrent;
    const float smax   = eta / phi * gdark_ *
                         (1.0f + powf(cdark / hillaffinity, hillcoef));

    const float Ar  = 1.0f - DT * sigma;
    const float Ap  = 1.0f - DT * phi;
    const float Pe  = DT * eta;
    const float Ac  = 1.0f - DT * beta;
    const float Kc  = DT * cur2ca * cgmp2cur;
    const float Acs = 1.0f - DT * betaSlow;
    const float Bcs = DT * betaSlow;
    const float inv_cd = 1.0f / cdark;
    const float inv_ha = 1.0f / hillaffinity;
    const float outk   = -0.5f * cgmp2cur;

    const float* __restrict__ xp = x   + (size_t)b * T_ * P_ + p;
    float*       __restrict__ op = out + (size_t)b * T_ * P_ + p;

    // initial state
    const float x0 = xp[0];
    float r  = x0 * gamma / sigma;
    float pv = (eta + r) / phi;
    float g  = gdark_;
    float s  = gdark_ * eta / phi;
    float c  = cdark;
    float cs = cdark;
    __builtin_nontemporal_store(0.0f, op);   // g_all[0] = 0 -> output 0

    if (cgmphill == 3.0f && hillcoef == 4.0f) {
        // ---- hot specialized path (uniform branch) ----
        auto step = [&](float xt, int oidx) {
            float r1  = fmaf(Ar, r, gamma * xt);
            float p1  = fmaf(Ap, pv, fmaf(DT, r, Pe));
            float g3  = g * g * g;
            float den = fmaf(cs, inv_cd, 1.0f);
            float c1  = fmaf(Ac, c, Kc * g3 * rcp_fast(den));
            float cs1 = fmaf(Acs, cs, Bcs * c);
            float yy  = c1 * inv_ha;
            float y2  = yy * yy;
            float y4  = y2 * y2;
            float s1  = smax * rcp_fast(1.0f + y4);
            float g1  = fmaf(DT, fmaf(-pv, g, s), g);
            __builtin_nontemporal_store(outk * (g1 * g1 * g1),
                                        op + (size_t)oidx * P_);
            r = r1; pv = p1; c = c1; cs = cs1; s = s1; g = g1;
        };

        constexpr int U = 16;   // chunk size; 63 chunks cover t=0..998 (+clamp)
        float B0[U], B1[U], B2[U], B3[U], B4[U];

#define SB __builtin_amdgcn_sched_barrier(0)
#define LOADCH(buf, chunk) do {                                          \
            const int _tn = (chunk) * U;                                 \
            _Pragma("unroll")                                            \
            for (int u = 0; u < U; ++u)                                  \
                buf[u] = xp[(size_t)(_tn + u) * P_];                     \
        } while (0)
#define LOADCL(buf, chunk) do {                                          \
            const int _tn = (chunk) * U;                                 \
            _Pragma("unroll")                                            \
            for (int u = 0; u < U; ++u) {                                \
                int _tt = _tn + u; _tt = _tt > 998 ? 998 : _tt;          \
                buf[u] = xp[(size_t)_tt * P_];                           \
            }                                                            \
        } while (0)
#define COMPCH(buf, chunk) do {                                          \
            const int _tb = (chunk) * U;                                 \
            _Pragma("unroll")                                            \
            for (int u = 0; u < U; ++u) step(buf[u], _tb + u + 1);       \
        } while (0)

        // prologue: fill depth-4 pipeline (chunks 0..3)
        LOADCH(B0, 0); LOADCH(B1, 1); LOADCH(B2, 2); LOADCH(B3, 3); SB;

        // phases 0..54: compute chunk p from B[p%5], load chunk p+4 into
        // B[(p+4)%5]. Unroll x5 -> rotation is compile-time, no reg copies.
        #pragma unroll 1
        for (int ci = 0; ci < 11; ++ci) {
            const int c0 = ci * 5;
            LOADCH(B4, c0 + 4); SB; COMPCH(B0, c0 + 0); SB;
            LOADCH(B0, c0 + 5); SB; COMPCH(B1, c0 + 1); SB;
            LOADCH(B1, c0 + 6); SB; COMPCH(B2, c0 + 2); SB;
            LOADCH(B2, c0 + 7); SB; COMPCH(B3, c0 + 3); SB;
            LOADCH(B3, c0 + 8); SB; COMPCH(B4, c0 + 4); SB;
        }
        // epilogue: phases 55..62 (chunk 62 is clamped, 7 live steps)
        LOADCH(B4, 59); SB; COMPCH(B0, 55); SB;
        LOADCH(B0, 60); SB; COMPCH(B1, 56); SB;
        LOADCH(B1, 61); SB; COMPCH(B2, 57); SB;
        LOADCL(B2, 62); SB; COMPCH(B3, 58); SB;
        COMPCH(B4, 59); COMPCH(B0, 60); COMPCH(B1, 61);
        #pragma unroll
        for (int u = 0; u < 7; ++u) step(B2[u], 62 * U + u + 1); // t=992..998

#undef SB
#undef LOADCH
#undef LOADCL
#undef COMPCH
    } else {
        // ---- generic fallback (exact powf; never taken for bench params) ----
        for (int t = 0; t < T_ - 1; ++t) {
            float xt  = xp[(size_t)t * P_];
            float r1  = r + DT * (-sigma * r) + gamma * xt;
            float p1  = pv + DT * (r + eta - phi * pv);
            float c1  = c + DT * (cur2ca * cgmp2cur * powf(g, cgmphill) /
                                  (1.0f + cs / cdark) - beta * c);
            float cs1 = cs - DT * (betaSlow * (cs - c));
            float s1  = smax / (1.0f + powf(c1 / hillaffinity, hillcoef));
            float g1  = g + DT * (s - pv * g);
            op[(size_t)(t + 1) * P_] = -(cgmp2cur * powf(g1, cgmphill)) * 0.5f;
            r = r1; pv = p1; c = c1; cs = cs1; s = s1; g = g1;
        }
    }
}

extern "C" void kernel_launch(void* const* d_in, const int* in_sizes, int n_in,
                              void* d_out, int out_size, void* d_ws, size_t ws_size,
                              hipStream_t stream) {
    const float* x = (const float*)d_in[0];
    prk_kernel<<<dim3(NCH / 64), dim3(64), 0, stream>>>(
        x,
        (const float*)d_in[1],  (const float*)d_in[2],  (const float*)d_in[3],
        (const float*)d_in[4],  (const float*)d_in[5],  (const float*)d_in[6],
        (const float*)d_in[7],  (const float*)d_in[8],  (const float*)d_in[9],
        (const float*)d_in[10], (const float*)d_in[11], (const float*)d_in[12],
        (float*)d_out);
}